// Round 1
// baseline (198.958 us; speedup 1.0000x reference)
//
#include <hip/hip_runtime.h>
#include <hip/hip_fp16.h>

#define L_SEQ 4096
#define BATCH 4
#define DIM 512
#define M_ROWS (L_SEQ * BATCH)          // 16384
#define SCALE 0.04419417382415922f      // 1/sqrt(512)
#define SLS 4097                         // star logits per batch (L+1)

typedef __attribute__((ext_vector_type(4))) float f32x4;
typedef __attribute__((ext_vector_type(8))) _Float16 f16x8;
typedef __attribute__((ext_vector_type(4))) _Float16 f16x4;

__device__ inline void gload16(const void* g, void* l) {
    __builtin_amdgcn_global_load_lds(
        (const __attribute__((address_space(1))) void*)g,
        (__attribute__((address_space(3))) void*)l, 16, 0, 0);
}

// ---------------- conversion kernels ----------------
__global__ __launch_bounds__(256) void conv_weights(
    const float* __restrict__ Wq, const float* __restrict__ Wk,
    const float* __restrict__ Wv, const float* __restrict__ Wo,
    const float* __restrict__ bq, const float* __restrict__ bk, const float* __restrict__ bv,
    _Float16* __restrict__ Wqkv, _Float16* __restrict__ Wof, float* __restrict__ bqkv)
{
    int i = blockIdx.x * 256 + threadIdx.x;          // < 1536*512
    {
        int r = i >> 9, c = i & 511;
        const float* W = (r < 512) ? Wq : (r < 1024 ? Wk : Wv);
        Wqkv[i] = (_Float16)W[(size_t)(r & 511) * 512 + c];
    }
    if (i < 512 * 512) Wof[i] = (_Float16)Wo[i];
    if (i < 1536) bqkv[i] = (i < 512) ? bq[i] : (i < 1024 ? bk[i - 512] : bv[i - 1024]);
}

__global__ __launch_bounds__(256) void conv_xe(
    const float* __restrict__ x, const float* __restrict__ e,
    _Float16* __restrict__ xh, _Float16* __restrict__ eh)
{
    size_t i = (size_t)blockIdx.x * 256 + threadIdx.x;   // < 2 * M*D/4
    const size_t NV = (size_t)M_ROWS * DIM / 4;
    const float* src; _Float16* dst; size_t j;
    if (i < NV) { src = x; dst = xh; j = i; } else { src = e; dst = eh; j = i - NV; }
    float4 v = ((const float4*)src)[j];
    f16x4 h = { (_Float16)v.x, (_Float16)v.y, (_Float16)v.z, (_Float16)v.w };
    ((f16x4*)dst)[j] = h;
}

// relay projections kr/vr (fp32, exact) + zero star accumulator
__global__ __launch_bounds__(256) void relay_proj(
    const float* __restrict__ relay,
    const float* __restrict__ Wk, const float* __restrict__ bk,
    const float* __restrict__ Wv, const float* __restrict__ bv,
    float* __restrict__ krvr, float* __restrict__ star)
{
    int o = blockIdx.x * 256 + threadIdx.x;          // < 4096
    int sel = o >> 11, rem = o & 2047, b = rem >> 9, j = rem & 511;
    const float* W = sel ? Wv : Wk;
    float s = sel ? bv[j] : bk[j];
    const float* rp = relay + (size_t)b * 512;
    const float* wr = W + (size_t)j * 512;
#pragma unroll 8
    for (int d = 0; d < 512; ++d) s += rp[d] * wr[d];
    krvr[o] = s;
    if (o < 2048) star[o] = 0.f;
}

// ---------------- GEMM: C[M,N] = A[M,K] * B[N,K]^T + bias ----------------
template<int OUT16>
__global__ __launch_bounds__(256) void gemm_bt(
    const _Float16* __restrict__ A, const _Float16* __restrict__ Bm,
    const float* __restrict__ bias, void* __restrict__ Cv,
    int M, int N, int K)
{
    __shared__ _Float16 lA[128 * 32];
    __shared__ _Float16 lB[128 * 32];
    const int tid = threadIdx.x;
    const int wave = tid >> 6, lane = tid & 63;
    const int row0 = blockIdx.x * 128;
    const int col0 = blockIdx.y * 128;
    const int wm = (wave >> 1) * 64, wn = (wave & 1) * 64;

    f32x4 acc[4][4];
#pragma unroll
    for (int i = 0; i < 4; ++i)
#pragma unroll
        for (int j = 0; j < 4; ++j) acc[i][j] = (f32x4)0.f;

    // staging: chunk = i*256 + wave*64 + lane covers tile elem [chunk*8 .. +8)
    const int c0 = wave * 64 + lane;
    const int c1 = 256 + c0;
    const int ar0 = c0 >> 2, ac0 = (c0 & 3) * 8;
    const int ar1 = c1 >> 2, ac1 = (c1 & 3) * 8;
    _Float16* dstA0 = lA + (wave * 64) * 8;           // wave-uniform LDS bases
    _Float16* dstA1 = lA + (256 + wave * 64) * 8;
    _Float16* dstB0 = lB + (wave * 64) * 8;
    _Float16* dstB1 = lB + (256 + wave * 64) * 8;

    const int nsteps = K >> 5;
    auto stage = [&](int k0) {
        gload16(A  + (size_t)(row0 + ar0) * K + k0 + ac0, dstA0);
        gload16(A  + (size_t)(row0 + ar1) * K + k0 + ac1, dstA1);
        gload16(Bm + (size_t)(col0 + ar0) * K + k0 + ac0, dstB0);
        gload16(Bm + (size_t)(col0 + ar1) * K + k0 + ac1, dstB1);
    };
    stage(0);

    for (int t = 0; t < nsteps; ++t) {
        __syncthreads();                              // staged tile visible (vmcnt drained)
        const int aro = (wm + (lane & 15)) * 32 + (lane >> 4) * 8;
        const int bro = (wn + (lane & 15)) * 32 + (lane >> 4) * 8;
        f16x8 af[4], bfr[4];
#pragma unroll
        for (int i = 0; i < 4; ++i) af[i]  = *(const f16x8*)(lA + aro + i * 16 * 32);
#pragma unroll
        for (int i = 0; i < 4; ++i) bfr[i] = *(const f16x8*)(lB + bro + i * 16 * 32);
        __syncthreads();                              // all waves done reading LDS
        if (t + 1 < nsteps) stage((t + 1) << 5);      // prefetch overlaps MFMA
#pragma unroll
        for (int mi = 0; mi < 4; ++mi)
#pragma unroll
            for (int ni = 0; ni < 4; ++ni)
                acc[mi][ni] = __builtin_amdgcn_mfma_f32_16x16x32_f16(
                    af[mi], bfr[ni], acc[mi][ni], 0, 0, 0);
    }

    // epilogue: D row = (lane>>4)*4 + r, col = lane&15
#pragma unroll
    for (int mi = 0; mi < 4; ++mi) {
#pragma unroll
        for (int ni = 0; ni < 4; ++ni) {
            const int col = col0 + wn + ni * 16 + (lane & 15);
            const float bb = bias[col];
#pragma unroll
            for (int r = 0; r < 4; ++r) {
                const int row = row0 + wm + mi * 16 + (lane >> 4) * 4 + r;
                float v = acc[mi][ni][r] + bb;
                if (OUT16) ((_Float16*)Cv)[(size_t)row * N + col] = (_Float16)v;
                else       ((float*)Cv)[(size_t)row * N + col] = v;
            }
        }
    }
}

// ---------------- ring (windowed) attention: one wave per (l,b) ----------------
__global__ __launch_bounds__(256) void ring_attn(
    const _Float16* __restrict__ qkv,    // [M,1536] q|k|v
    const _Float16* __restrict__ ekv,    // [M,1024] ke|ve
    const float* __restrict__ krvr,      // [2][B][512]
    _Float16* __restrict__ ring)         // [M,512]
{
    const int wid = (blockIdx.x << 2) + (threadIdx.x >> 6);   // row r = l*B+b
    const int lane = threadIdx.x & 63;
    const int r = wid, b = r & 3, l = r >> 2;
    const int d0 = lane << 3;

    float q[8];
    {
        f16x8 t = *(const f16x8*)(qkv + (size_t)r * 1536 + d0);
#pragma unroll
        for (int i = 0; i < 8; ++i) q[i] = (float)t[i];
    }
    const bool has0 = (l > 0), has2 = (l < L_SEQ - 1);

    auto dotk = [&](const _Float16* kp) -> float {
        f16x8 t = *(const f16x8*)(kp + d0);
        float s = 0.f;
#pragma unroll
        for (int i = 0; i < 8; ++i) s += q[i] * (float)t[i];
#pragma unroll
        for (int o = 32; o; o >>= 1) s += __shfl_xor(s, o);
        return s;
    };

    float lg[5];
    lg[0] = has0 ? dotk(qkv + (size_t)(r - 4) * 1536 + 512) : 0.f;  // zero key -> logit 0
    lg[1] = dotk(qkv + (size_t)r * 1536 + 512);
    lg[2] = has2 ? dotk(qkv + (size_t)(r + 4) * 1536 + 512) : 0.f;
    lg[3] = dotk(ekv + (size_t)r * 1024);
    {
        const float* kp = krvr + (size_t)b * 512 + d0;
        float s = 0.f;
#pragma unroll
        for (int i = 0; i < 8; ++i) s += q[i] * kp[i];
#pragma unroll
        for (int o = 32; o; o >>= 1) s += __shfl_xor(s, o);
        lg[4] = s;
    }

    float li[5], m = -1e30f;
#pragma unroll
    for (int w = 0; w < 5; ++w) { li[w] = lg[w] * SCALE; m = fmaxf(m, li[w]); }
    float ew[5], Z = 0.f;
#pragma unroll
    for (int w = 0; w < 5; ++w) { ew[w] = expf(li[w] - m); Z += ew[w]; }
    const float inv = 1.f / Z;

    float o8[8] = {0, 0, 0, 0, 0, 0, 0, 0};
    auto addv = [&](const _Float16* vp, float a) {
        f16x8 t = *(const f16x8*)(vp + d0);
#pragma unroll
        for (int i = 0; i < 8; ++i) o8[i] += a * (float)t[i];
    };
    if (has0) addv(qkv + (size_t)(r - 4) * 1536 + 1024, ew[0] * inv);
    addv(qkv + (size_t)r * 1536 + 1024, ew[1] * inv);
    if (has2) addv(qkv + (size_t)(r + 4) * 1536 + 1024, ew[2] * inv);
    addv(ekv + (size_t)r * 1024 + 512, ew[3] * inv);
    {
        const float* vp = krvr + 2048 + (size_t)b * 512 + d0;
        const float a = ew[4] * inv;
#pragma unroll
        for (int i = 0; i < 8; ++i) o8[i] += a * vp[i];
    }
    f16x8 res;
#pragma unroll
    for (int i = 0; i < 8; ++i) res[i] = (_Float16)o8[i];
    *(f16x8*)(ring + (size_t)r * 512 + d0) = res;
}

// ---------------- star attention ----------------
__global__ __launch_bounds__(256) void star_logits(
    const float* __restrict__ relay, const _Float16* __restrict__ qkv,
    float* __restrict__ slog)
{
    const int wid = (blockIdx.x << 2) + (threadIdx.x >> 6);   // r = n*B+b
    const int lane = threadIdx.x & 63;
    const int b = wid & 3, n = wid >> 2;
    const int d0 = lane << 3;
    const float* rp = relay + (size_t)b * 512 + d0;
    f16x8 t = *(const f16x8*)(qkv + (size_t)wid * 1536 + 512 + d0);
    float s = 0.f;
#pragma unroll
    for (int i = 0; i < 8; ++i) s += rp[i] * (float)t[i];
#pragma unroll
    for (int o = 32; o; o >>= 1) s += __shfl_xor(s, o);
    if (lane == 0) slog[(size_t)b * SLS + n] = s * SCALE;
}

__global__ __launch_bounds__(256) void star_softmax(
    const float* __restrict__ relay, const float* __restrict__ krvr,
    float* __restrict__ slog)
{
    const int b = blockIdx.x, t = threadIdx.x;
    __shared__ float red[256];
    float* sl = slog + (size_t)b * SLS;

    // logit for the relay key itself
    float p = 0.f;
    for (int d = t; d < 512; d += 256) p += relay[(size_t)b * 512 + d] * krvr[(size_t)b * 512 + d];
    red[t] = p; __syncthreads();
    for (int s = 128; s; s >>= 1) { if (t < s) red[t] += red[t + s]; __syncthreads(); }
    if (t == 0) sl[SLS - 1] = red[0] * SCALE;
    __syncthreads();

    float m = -1e30f;
    for (int n = t; n < SLS; n += 256) m = fmaxf(m, sl[n]);
    red[t] = m; __syncthreads();
    for (int s = 128; s; s >>= 1) { if (t < s) red[t] = fmaxf(red[t], red[t + s]); __syncthreads(); }
    m = red[0]; __syncthreads();

    float z = 0.f;
    for (int n = t; n < SLS; n += 256) z += expf(sl[n] - m);
    red[t] = z; __syncthreads();
    for (int s = 128; s; s >>= 1) { if (t < s) red[t] += red[t + s]; __syncthreads(); }
    const float inv = 1.f / red[0]; __syncthreads();

    for (int n = t; n < SLS; n += 256) sl[n] = expf(sl[n] - m) * inv;
}

__global__ __launch_bounds__(256) void star_out(
    const float* __restrict__ slog, const _Float16* __restrict__ qkv,
    const float* __restrict__ krvr, float* __restrict__ star)
{
    const int nc = blockIdx.x, b = blockIdx.y;           // nc < 64
    const int d1 = threadIdx.x, d2 = threadIdx.x + 256;
    const float* al = slog + (size_t)b * SLS;
    float a1 = 0.f, a2 = 0.f;
    for (int i = 0; i < 64; ++i) {
        const int n = nc * 64 + i;
        const float a = al[n];
        const _Float16* v = qkv + (size_t)(n * 4 + b) * 1536 + 1024;
        a1 += a * (float)v[d1];
        a2 += a * (float)v[d2];
    }
    if (nc == 63) {
        const float a = al[SLS - 1];
        const float* vr = krvr + 2048 + (size_t)b * 512;
        a1 += a * vr[d1];
        a2 += a * vr[d2];
    }
    atomicAdd(&star[(size_t)b * 512 + d1], a1);
    atomicAdd(&star[(size_t)b * 512 + d2], a2);
}

__global__ __launch_bounds__(256) void star_proj(
    const float* __restrict__ star, const float* __restrict__ Wo,
    const float* __restrict__ bo, float* __restrict__ out1)
{
    const int o = blockIdx.x * 256 + threadIdx.x;        // < 2048
    const int b = o >> 9, j = o & 511;
    float s = bo[j];
    const float* sp = star + (size_t)b * 512;
    const float* wr = Wo + (size_t)j * 512;
#pragma unroll 8
    for (int d = 0; d < 512; ++d) s += sp[d] * wr[d];
    out1[o] = s;
}

// ---------------- host launch ----------------
extern "C" void kernel_launch(void* const* d_in, const int* in_sizes, int n_in,
                              void* d_out, int out_size, void* d_ws, size_t ws_size,
                              hipStream_t stream) {
    const float* x     = (const float*)d_in[0];
    const float* e     = (const float*)d_in[1];
    const float* relay = (const float*)d_in[2];
    const float* Wq    = (const float*)d_in[3];
    const float* bq    = (const float*)d_in[4];
    const float* Wk    = (const float*)d_in[5];
    const float* bk    = (const float*)d_in[6];
    const float* Wv    = (const float*)d_in[7];
    const float* bv    = (const float*)d_in[8];
    const float* Wo    = (const float*)d_in[9];
    const float* bo    = (const float*)d_in[10];
    float* out = (float*)d_out;

    // workspace layout (256B aligned)
    size_t off = 0;
    auto alloc = [&](size_t bytes) {
        void* p = (char*)d_ws + off;
        off += (bytes + 255) & ~(size_t)255;
        return p;
    };
    _Float16* Wqkv = (_Float16*)alloc((size_t)1536 * 512 * 2);
    _Float16* Wof  = (_Float16*)alloc((size_t)512 * 512 * 2);
    float*    bqkv = (float*)   alloc(1536 * 4);
    _Float16* xh   = (_Float16*)alloc((size_t)M_ROWS * 512 * 2);
    _Float16* eh   = (_Float16*)alloc((size_t)M_ROWS * 512 * 2);
    _Float16* qkv  = (_Float16*)alloc((size_t)M_ROWS * 1536 * 2);
    _Float16* ekv  = (_Float16*)alloc((size_t)M_ROWS * 1024 * 2);
    float*    krvr = (float*)   alloc(2 * 4 * 512 * 4);
    float*    slog = (float*)   alloc((size_t)4 * SLS * 4);
    float*    star = (float*)   alloc(4 * 512 * 4);
    _Float16* ringb = xh;   // alias: xh is dead after the qkv GEMM

    conv_weights<<<3072, 256, 0, stream>>>(Wq, Wk, Wv, Wo, bq, bk, bv, Wqkv, Wof, bqkv);
    conv_xe<<<16384, 256, 0, stream>>>(x, e, xh, eh);
    relay_proj<<<16, 256, 0, stream>>>(relay, Wk, bk, Wv, bv, krvr, star);

    gemm_bt<1><<<dim3(M_ROWS / 128, 1536 / 128), 256, 0, stream>>>(
        xh, Wqkv, bqkv, qkv, M_ROWS, 1536, 512);
    gemm_bt<1><<<dim3(M_ROWS / 128, 1024 / 128), 256, 0, stream>>>(
        eh, Wqkv + (size_t)512 * 512, bqkv + 512, ekv, M_ROWS, 1024, 512);

    ring_attn<<<M_ROWS / 4, 256, 0, stream>>>(qkv, ekv, krvr, ringb);

    star_logits<<<M_ROWS / 4, 256, 0, stream>>>(relay, qkv, slog);
    star_softmax<<<4, 256, 0, stream>>>(relay, krvr, slog);
    star_out<<<dim3(64, 4), 256, 0, stream>>>(slog, qkv, krvr, star);

    gemm_bt<0><<<dim3(M_ROWS / 128, 512 / 128), 256, 0, stream>>>(
        ringb, Wof, bo, out, M_ROWS, 512, 512);
    star_proj<<<8, 256, 0, stream>>>(star, Wo, bo, out + (size_t)M_ROWS * 512);
}

// Round 2
// 160.731 us; speedup vs baseline: 1.2378x; 1.2378x over previous
//
#include <hip/hip_runtime.h>
#include <hip/hip_fp16.h>

#define L_SEQ 4096
#define BATCH 4
#define DIM 512
#define M_ROWS (L_SEQ * BATCH)          // 16384
#define SCALE 0.04419417382415922f      // 1/sqrt(512)
#define SLS 4097                         // star logits per batch (L+1)

typedef __attribute__((ext_vector_type(4))) float f32x4;
typedef __attribute__((ext_vector_type(8))) _Float16 f16x8;
typedef __attribute__((ext_vector_type(4))) _Float16 f16x4;

__device__ inline void gload16(const void* g, void* l) {
    __builtin_amdgcn_global_load_lds(
        (const __attribute__((address_space(1))) void*)g,
        (__attribute__((address_space(3))) void*)l, 16, 0, 0);
}

__device__ inline float wred_sum(float s) {
#pragma unroll
    for (int o = 32; o; o >>= 1) s += __shfl_xor(s, o);
    return s;
}
__device__ inline float wred_max(float s) {
#pragma unroll
    for (int o = 32; o; o >>= 1) s = fmaxf(s, __shfl_xor(s, o));
    return s;
}

// ---------------- prep: all f32->f16 conversions + bias pack ----------------
__global__ __launch_bounds__(256) void prep(
    const float* __restrict__ x, const float* __restrict__ e,
    const float* __restrict__ Wq, const float* __restrict__ Wk,
    const float* __restrict__ Wv, const float* __restrict__ Wo,
    const float* __restrict__ bq, const float* __restrict__ bk, const float* __restrict__ bv,
    _Float16* __restrict__ xh, _Float16* __restrict__ eh,
    _Float16* __restrict__ Wqkv, _Float16* __restrict__ Wof, float* __restrict__ bqkv)
{
    const int bid = blockIdx.x;
    if (bid < 16384) {                       // x,e conversion as float4
        size_t i = (size_t)bid * 256 + threadIdx.x;   // < 2*2097152
        const size_t NV = (size_t)M_ROWS * DIM / 4;
        const float* src; _Float16* dst; size_t j;
        if (i < NV) { src = x; dst = xh; j = i; } else { src = e; dst = eh; j = i - NV; }
        float4 v = ((const float4*)src)[j];
        f16x4 h = { (_Float16)v.x, (_Float16)v.y, (_Float16)v.z, (_Float16)v.w };
        ((f16x4*)dst)[j] = h;
    } else {                                 // weights + bias
        int i = (bid - 16384) * 256 + threadIdx.x;    // < 786432
        {
            int r = i >> 9, c = i & 511;
            const float* W = (r < 512) ? Wq : (r < 1024 ? Wk : Wv);
            Wqkv[i] = (_Float16)W[(size_t)(r & 511) * 512 + c];
        }
        if (i < 512 * 512) Wof[i] = (_Float16)Wo[i];
        if (i < 1536) bqkv[i] = (i < 512) ? bq[i] : (i < 1024 ? bk[i - 512] : bv[i - 1024]);
    }
}

// relay k/v projections (fp32 exact), wave-per-output; also zero star accum
__global__ __launch_bounds__(256) void relay_proj(
    const float* __restrict__ relay,
    const float* __restrict__ Wk, const float* __restrict__ bk,
    const float* __restrict__ Wv, const float* __restrict__ bv,
    float* __restrict__ krvr, float* __restrict__ star)
{
    const int o = (blockIdx.x << 2) + (threadIdx.x >> 6);   // 0..4095
    const int lane = threadIdx.x & 63;
    const int sel = o >> 11, rem = o & 2047, b = rem >> 9, j = rem & 511;
    const float* W = sel ? Wv : Wk;
    const float* wr = W + (size_t)j * 512 + lane * 8;
    const float* rp = relay + (size_t)b * 512 + lane * 8;
    float4 w0 = *(const float4*)wr,  w1 = *(const float4*)(wr + 4);
    float4 r0 = *(const float4*)rp,  r1 = *(const float4*)(rp + 4);
    float s = w0.x * r0.x + w0.y * r0.y + w0.z * r0.z + w0.w * r0.w
            + w1.x * r1.x + w1.y * r1.y + w1.z * r1.z + w1.w * r1.w;
    s = wred_sum(s);
    if (lane == 0) {
        krvr[o] = s + (sel ? bv[j] : bk[j]);
        if (o < 2048) star[o] = 0.f;
    }
}

// ---------------- GEMM: C[M,N] = A[M,K] * B[N,K]^T + bias ----------------
template<int OUT16>
__global__ __launch_bounds__(256) void gemm_bt(
    const _Float16* __restrict__ A, const _Float16* __restrict__ Bm,
    const float* __restrict__ bias, void* __restrict__ Cv,
    int M, int N, int K)
{
    __shared__ _Float16 lA[128 * 32];
    __shared__ _Float16 lB[128 * 32];
    const int tid = threadIdx.x;
    const int wave = tid >> 6, lane = tid & 63;
    const int row0 = blockIdx.x * 128;
    const int col0 = blockIdx.y * 128;
    const int wm = (wave >> 1) * 64, wn = (wave & 1) * 64;

    f32x4 acc[4][4];
#pragma unroll
    for (int i = 0; i < 4; ++i)
#pragma unroll
        for (int j = 0; j < 4; ++j) acc[i][j] = (f32x4)0.f;

    const int c0 = wave * 64 + lane;
    const int c1 = 256 + c0;
    const int ar0 = c0 >> 2, ac0 = (c0 & 3) * 8;
    const int ar1 = c1 >> 2, ac1 = (c1 & 3) * 8;
    _Float16* dstA0 = lA + (wave * 64) * 8;
    _Float16* dstA1 = lA + (256 + wave * 64) * 8;
    _Float16* dstB0 = lB + (wave * 64) * 8;
    _Float16* dstB1 = lB + (256 + wave * 64) * 8;

    const int nsteps = K >> 5;
    auto stage = [&](int k0) {
        gload16(A  + (size_t)(row0 + ar0) * K + k0 + ac0, dstA0);
        gload16(A  + (size_t)(row0 + ar1) * K + k0 + ac1, dstA1);
        gload16(Bm + (size_t)(col0 + ar0) * K + k0 + ac0, dstB0);
        gload16(Bm + (size_t)(col0 + ar1) * K + k0 + ac1, dstB1);
    };
    stage(0);

    for (int t = 0; t < nsteps; ++t) {
        __syncthreads();
        const int aro = (wm + (lane & 15)) * 32 + (lane >> 4) * 8;
        const int bro = (wn + (lane & 15)) * 32 + (lane >> 4) * 8;
        f16x8 af[4], bfr[4];
#pragma unroll
        for (int i = 0; i < 4; ++i) af[i]  = *(const f16x8*)(lA + aro + i * 16 * 32);
#pragma unroll
        for (int i = 0; i < 4; ++i) bfr[i] = *(const f16x8*)(lB + bro + i * 16 * 32);
        __syncthreads();
        if (t + 1 < nsteps) stage((t + 1) << 5);
#pragma unroll
        for (int mi = 0; mi < 4; ++mi)
#pragma unroll
            for (int ni = 0; ni < 4; ++ni)
                acc[mi][ni] = __builtin_amdgcn_mfma_f32_16x16x32_f16(
                    af[mi], bfr[ni], acc[mi][ni], 0, 0, 0);
    }

#pragma unroll
    for (int mi = 0; mi < 4; ++mi) {
#pragma unroll
        for (int ni = 0; ni < 4; ++ni) {
            const int col = col0 + wn + ni * 16 + (lane & 15);
            const float bb = bias[col];
#pragma unroll
            for (int r = 0; r < 4; ++r) {
                const int row = row0 + wm + mi * 16 + (lane >> 4) * 4 + r;
                float v = acc[mi][ni][r] + bb;
                if (OUT16) ((_Float16*)Cv)[(size_t)row * N + col] = (_Float16)v;
                else       ((float*)Cv)[(size_t)row * N + col] = v;
            }
        }
    }
}

// ------- ring attention (one wave per (l,b)) + fused star logits -------
__global__ __launch_bounds__(256) void ring_attn(
    const _Float16* __restrict__ qkv,    // [M,1536] q|k|v
    const _Float16* __restrict__ ekv,    // [M,1024] ke|ve
    const float* __restrict__ krvr,      // [2][B][512]
    const float* __restrict__ relay,     // [B,512]
    _Float16* __restrict__ ring,         // [M,512]
    float* __restrict__ slog)            // [B,SLS]
{
    const int wid = (blockIdx.x << 2) + (threadIdx.x >> 6);   // row r = l*B+b
    const int lane = threadIdx.x & 63;
    const int r = wid, b = r & 3, l = r >> 2;
    const int d0 = lane << 3;

    float q[8], rl[8];
    {
        f16x8 t = *(const f16x8*)(qkv + (size_t)r * 1536 + d0);
#pragma unroll
        for (int i = 0; i < 8; ++i) q[i] = (float)t[i];
        const float* rp = relay + (size_t)b * 512 + d0;
        float4 a = *(const float4*)rp, c = *(const float4*)(rp + 4);
        rl[0] = a.x; rl[1] = a.y; rl[2] = a.z; rl[3] = a.w;
        rl[4] = c.x; rl[5] = c.y; rl[6] = c.z; rl[7] = c.w;
    }
    const bool has0 = (l > 0), has2 = (l < L_SEQ - 1);

    auto dotk = [&](const _Float16* kp) -> float {
        f16x8 t = *(const f16x8*)(kp + d0);
        float s = 0.f;
#pragma unroll
        for (int i = 0; i < 8; ++i) s += q[i] * (float)t[i];
        return wred_sum(s);
    };

    float lg[5];
    lg[0] = has0 ? dotk(qkv + (size_t)(r - 4) * 1536 + 512) : 0.f;  // zero key -> logit 0
    lg[2] = has2 ? dotk(qkv + (size_t)(r + 4) * 1536 + 512) : 0.f;
    lg[3] = dotk(ekv + (size_t)r * 1024);
    {   // self k row: ring logit + star logit (relay . k)
        f16x8 t = *(const f16x8*)(qkv + (size_t)r * 1536 + 512 + d0);
        float s1 = 0.f, s2 = 0.f;
#pragma unroll
        for (int i = 0; i < 8; ++i) { float kf = (float)t[i]; s1 += q[i] * kf; s2 += rl[i] * kf; }
#pragma unroll
        for (int o = 32; o; o >>= 1) { s1 += __shfl_xor(s1, o); s2 += __shfl_xor(s2, o); }
        lg[1] = s1;
        if (lane == 0) slog[(size_t)b * SLS + l] = s2 * SCALE;
    }
    {   // relay key
        const float* kp = krvr + (size_t)b * 512 + d0;
        float s = 0.f;
#pragma unroll
        for (int i = 0; i < 8; ++i) s += q[i] * kp[i];
        lg[4] = wred_sum(s);
    }

    float li[5], m = -1e30f;
#pragma unroll
    for (int w = 0; w < 5; ++w) { li[w] = lg[w] * SCALE; m = fmaxf(m, li[w]); }
    float ew[5], Z = 0.f;
#pragma unroll
    for (int w = 0; w < 5; ++w) { ew[w] = expf(li[w] - m); Z += ew[w]; }
    const float inv = 1.f / Z;

    float o8[8] = {0, 0, 0, 0, 0, 0, 0, 0};
    auto addv = [&](const _Float16* vp, float a) {
        f16x8 t = *(const f16x8*)(vp + d0);
#pragma unroll
        for (int i = 0; i < 8; ++i) o8[i] += a * (float)t[i];
    };
    if (has0) addv(qkv + (size_t)(r - 4) * 1536 + 1024, ew[0] * inv);
    addv(qkv + (size_t)r * 1536 + 1024, ew[1] * inv);
    if (has2) addv(qkv + (size_t)(r + 4) * 1536 + 1024, ew[2] * inv);
    addv(ekv + (size_t)r * 1024 + 512, ew[3] * inv);
    {
        const float* vp = krvr + 2048 + (size_t)b * 512 + d0;
        const float a = ew[4] * inv;
#pragma unroll
        for (int i = 0; i < 8; ++i) o8[i] += a * vp[i];
    }
    f16x8 res;
#pragma unroll
    for (int i = 0; i < 8; ++i) res[i] = (_Float16)o8[i];
    *(f16x8*)(ring + (size_t)r * 512 + d0) = res;
}

// ---------------- star softmax: one 1024-thread block per batch ----------------
__global__ __launch_bounds__(1024) void star_softmax(
    const float* __restrict__ relay, const float* __restrict__ krvr,
    float* __restrict__ slog)
{
    const int b = blockIdx.x, t = threadIdx.x, lane = t & 63, w = t >> 6;
    __shared__ float red[16];
    __shared__ float bc[2];
    float* sl = slog + (size_t)b * SLS;

    // relay self-logit (kept in LDS, not round-tripped through global)
    float p = 0.f;
    if (t < 512) p = relay[(size_t)b * 512 + t] * krvr[(size_t)b * 512 + t];
    p = wred_sum(p);
    if (lane == 0) red[w] = p;
    __syncthreads();
    if (t == 0) { float s = 0.f; for (int i = 0; i < 16; ++i) s += red[i]; bc[0] = s * SCALE; }
    __syncthreads();
    const float selfl = bc[0];
    __syncthreads();

    float v[4];
#pragma unroll
    for (int i = 0; i < 4; ++i) v[i] = sl[t + i * 1024];

    float m = selfl;
#pragma unroll
    for (int i = 0; i < 4; ++i) m = fmaxf(m, v[i]);
    m = wred_max(m);
    if (lane == 0) red[w] = m;
    __syncthreads();
    if (t == 0) { float mm = red[0]; for (int i = 1; i < 16; ++i) mm = fmaxf(mm, red[i]); bc[1] = mm; }
    __syncthreads();
    m = bc[1];

    float ev[4], z = (t == 0) ? expf(selfl - m) : 0.f;
#pragma unroll
    for (int i = 0; i < 4; ++i) { ev[i] = expf(v[i] - m); z += ev[i]; }
    z = wred_sum(z);
    if (lane == 0) red[w] = z;
    __syncthreads();
    if (t == 0) { float s = 0.f; for (int i = 0; i < 16; ++i) s += red[i]; bc[0] = 1.f / s; }
    __syncthreads();
    const float inv = bc[0];

#pragma unroll
    for (int i = 0; i < 4; ++i) sl[t + i * 1024] = ev[i] * inv;
    if (t == 0) sl[SLS - 1] = expf(selfl - m) * inv;
}

// ------- star weighted V-sum: wave per (chunk,b), coalesced row loads -------
__global__ __launch_bounds__(256) void star_out(
    const float* __restrict__ slog, const _Float16* __restrict__ qkv,
    const float* __restrict__ krvr, float* __restrict__ star)
{
    const int b = threadIdx.x >> 6, lane = threadIdx.x & 63;
    const int chunk = blockIdx.x;                 // 64 chunks x 64 n each
    const int d0 = lane << 3;
    const float* al = slog + (size_t)b * SLS;
    float acc[8] = {0, 0, 0, 0, 0, 0, 0, 0};
#pragma unroll 4
    for (int i = 0; i < 64; ++i) {
        const int n = chunk * 64 + i;
        const float a = al[n];
        f16x8 v = *(const f16x8*)(qkv + (size_t)(n * 4 + b) * 1536 + 1024 + d0);
#pragma unroll
        for (int j = 0; j < 8; ++j) acc[j] += a * (float)v[j];
    }
    if (chunk == 63) {
        const float a = al[SLS - 1];
        const float* vr = krvr + 2048 + (size_t)b * 512 + d0;
#pragma unroll
        for (int j = 0; j < 8; ++j) acc[j] += a * vr[j];
    }
#pragma unroll
    for (int j = 0; j < 8; ++j) atomicAdd(&star[(size_t)b * 512 + d0 + j], acc[j]);
}

// ---------------- star projection: wave per output ----------------
__global__ __launch_bounds__(256) void star_proj(
    const float* __restrict__ star, const float* __restrict__ Wo,
    const float* __restrict__ bo, float* __restrict__ out1)
{
    const int o = (blockIdx.x << 2) + (threadIdx.x >> 6);   // 0..2047
    const int lane = threadIdx.x & 63;
    const int b = o >> 9, j = o & 511;
    const float* sp = star + (size_t)b * 512 + lane * 8;
    const float* wr = Wo + (size_t)j * 512 + lane * 8;
    float4 w0 = *(const float4*)wr,  w1 = *(const float4*)(wr + 4);
    float4 s0 = *(const float4*)sp,  s1 = *(const float4*)(sp + 4);
    float s = w0.x * s0.x + w0.y * s0.y + w0.z * s0.z + w0.w * s0.w
            + w1.x * s1.x + w1.y * s1.y + w1.z * s1.z + w1.w * s1.w;
    s = wred_sum(s);
    if (lane == 0) out1[o] = s + bo[j];
}

// ---------------- host launch ----------------
extern "C" void kernel_launch(void* const* d_in, const int* in_sizes, int n_in,
                              void* d_out, int out_size, void* d_ws, size_t ws_size,
                              hipStream_t stream) {
    const float* x     = (const float*)d_in[0];
    const float* e     = (const float*)d_in[1];
    const float* relay = (const float*)d_in[2];
    const float* Wq    = (const float*)d_in[3];
    const float* bq    = (const float*)d_in[4];
    const float* Wk    = (const float*)d_in[5];
    const float* bk    = (const float*)d_in[6];
    const float* Wv    = (const float*)d_in[7];
    const float* bv    = (const float*)d_in[8];
    const float* Wo    = (const float*)d_in[9];
    const float* bo    = (const float*)d_in[10];
    float* out = (float*)d_out;

    size_t off = 0;
    auto alloc = [&](size_t bytes) {
        void* p = (char*)d_ws + off;
        off += (bytes + 255) & ~(size_t)255;
        return p;
    };
    _Float16* Wqkv = (_Float16*)alloc((size_t)1536 * 512 * 2);
    _Float16* Wof  = (_Float16*)alloc((size_t)512 * 512 * 2);
    float*    bqkv = (float*)   alloc(1536 * 4);
    _Float16* xh   = (_Float16*)alloc((size_t)M_ROWS * 512 * 2);
    _Float16* eh   = (_Float16*)alloc((size_t)M_ROWS * 512 * 2);
    _Float16* qkv  = (_Float16*)alloc((size_t)M_ROWS * 1536 * 2);
    _Float16* ekv  = (_Float16*)alloc((size_t)M_ROWS * 1024 * 2);
    float*    krvr = (float*)   alloc(2 * 4 * 512 * 4);
    float*    slog = (float*)   alloc((size_t)4 * SLS * 4);
    float*    star = (float*)   alloc(4 * 512 * 4);
    _Float16* ringb = xh;   // alias: xh is dead after the qkv GEMM

    prep<<<16384 + 3072, 256, 0, stream>>>(x, e, Wq, Wk, Wv, Wo, bq, bk, bv,
                                           xh, eh, Wqkv, Wof, bqkv);
    relay_proj<<<1024, 256, 0, stream>>>(relay, Wk, bk, Wv, bv, krvr, star);

    gemm_bt<1><<<dim3(M_ROWS / 128, 1536 / 128), 256, 0, stream>>>(
        xh, Wqkv, bqkv, qkv, M_ROWS, 1536, 512);
    gemm_bt<1><<<dim3(M_ROWS / 128, 1024 / 128), 256, 0, stream>>>(
        eh, Wqkv + (size_t)512 * 512, bqkv + 512, ekv, M_ROWS, 1024, 512);

    ring_attn<<<M_ROWS / 4, 256, 0, stream>>>(qkv, ekv, krvr, relay, ringb, slog);

    star_softmax<<<4, 1024, 0, stream>>>(relay, krvr, slog);
    star_out<<<64, 256, 0, stream>>>(slog, qkv, krvr, star);

    gemm_bt<0><<<dim3(M_ROWS / 128, 512 / 128), 256, 0, stream>>>(
        ringb, Wof, bo, out, M_ROWS, 512, 512);
    star_proj<<<512, 256, 0, stream>>>(star, Wo, bo, out + (size_t)M_ROWS * 512);
}